// Round 3
// baseline (12881.514 us; speedup 1.0000x reference)
//
#include <hip/hip_runtime.h>
#include <hip/hip_bf16.h>

#define IN_F 32
#define HID 64
#define OUTF 16
#define C1 67                      // 2*IN + 3
#define EPW 8                      // edges per wave per iteration
#define ORD_NEG_INF 0x007FFFFFu    // ordenc(-inf)

// monotone float -> uint map so unsigned max == float max
__device__ __forceinline__ unsigned ordenc(float v) {
  unsigned b = __float_as_uint(v);
  return (b & 0x80000000u) ? ~b : (b | 0x80000000u);
}
__device__ __forceinline__ float orddec(unsigned u) {
  unsigned b = (u & 0x80000000u) ? (u & 0x7FFFFFFFu) : ~u;
  return __uint_as_float(b);
}

__global__ __launch_bounds__(256) void init_agg_kernel(unsigned* __restrict__ agg, int n) {
  int i = blockIdx.x * blockDim.x + threadIdx.x;
  if (i < n) agg[i] = ORD_NEG_INF;
}

// Per-wave independent pipeline, NO block barriers.
// Lane k owns output channel k. W1/W2 columns in registers.
// tmp trick: stage [x_i | x_j | ea] and fold the (x_j - x_i) subtraction into
// the weights: w1r[c<32] = W1[c] - W1[32+c]. One x-load per lane per edge.
__global__ __launch_bounds__(256) void edge_kernel(
    const float* __restrict__ x,           // [N, 32]
    const int* __restrict__ ei,            // [2, E]
    const float* __restrict__ ea,          // [E, 3]
    const float* __restrict__ W1,          // [67, 64]
    const float* __restrict__ b1,          // [64]
    const float* __restrict__ W2,          // [64, 64]
    const float* __restrict__ b2,          // [64]
    unsigned* __restrict__ agg,            // [N, 64] ord-encoded
    int E)
{
  __shared__ float tmps[4][C1][EPW];  // [wave][c][edge]  ~2.1 KB/wave
  __shared__ float hs[4][HID][EPW];   // [wave][j][edge]  2 KB/wave

  const int wave = threadIdx.x >> 6;
  const int lane = threadIdx.x & 63;

  // effective W1 columns (x_j - x_i folded in)
  float w1r[C1];
#pragma unroll
  for (int c = 0; c < 32; ++c) w1r[c] = W1[c * HID + lane] - W1[(32 + c) * HID + lane];
#pragma unroll
  for (int c = 32; c < C1; ++c) w1r[c] = W1[c * HID + lane];
  float w2r[HID];
#pragma unroll
  for (int j = 0; j < HID; ++j) w2r[j] = W2[j * HID + lane];
  const float b1v = b1[lane];
  const float b2v = b2[lane];

  const int col = lane & 31;               // my x column
  const bool side_dst = (lane < 32);       // lanes 0-31 stage x_i, 32-63 stage x_j

  const int gwave = (blockIdx.x << 2) | wave;
  const int stride = gridDim.x * 4 * EPW;

  int dn[EPW]; float xvn[EPW]; float ean = 0.f;

  // ---- prefetch iteration 0 ----
  {
    int e0 = gwave * EPW;
#pragma unroll
    for (int i = 0; i < EPW; ++i) {
      int e = e0 + i;
      if (e < E) {
        int s = ei[e];
        int d = ei[E + e];
        dn[i] = d;
        int row = side_dst ? d : s;
        xvn[i] = x[row * IN_F + col];
      } else dn[i] = -1;
    }
    if (lane < 3 * EPW && (e0 + lane / 3) < E) ean = ea[e0 * 3 + lane];
  }

  for (int e0 = gwave * EPW; e0 < E; e0 += stride) {
    // ---- consume prefetched regs: stage into per-wave LDS ----
    int dv[EPW]; float eav = ean;
#pragma unroll
    for (int i = 0; i < EPW; ++i) dv[i] = dn[i];
    {
      float4 t0, t1;
      t0.x = xvn[0]; t0.y = xvn[1]; t0.z = xvn[2]; t0.w = xvn[3];
      t1.x = xvn[4]; t1.y = xvn[5]; t1.z = xvn[6]; t1.w = xvn[7];
      ((float4*)&tmps[wave][lane][0])[0] = t0;
      ((float4*)&tmps[wave][lane][0])[1] = t1;
    }
    if (lane < 3 * EPW) tmps[wave][2 * IN_F + (lane % 3)][lane / 3] = eav;
    __builtin_amdgcn_wave_barrier();

    // ---- issue prefetch for next iteration (latency hidden by FMAs below) ----
    {
      int e1 = e0 + stride;
      if (e1 < E) {
#pragma unroll
        for (int i = 0; i < EPW; ++i) {
          int e = e1 + i;
          if (e < E) {
            int s = ei[e];
            int d = ei[E + e];
            dn[i] = d;
            int row = side_dst ? d : s;
            xvn[i] = x[row * IN_F + col];
          } else dn[i] = -1;
        }
        if (lane < 3 * EPW && (e1 + lane / 3) < E) ean = ea[e1 * 3 + lane];
      }
    }

    // ---- layer 1: h = relu(tmp @ W1' + b1) ----
    float a[EPW];
#pragma unroll
    for (int i = 0; i < EPW; ++i) a[i] = b1v;
#pragma unroll
    for (int c = 0; c < C1; ++c) {
      const float4 t0 = ((const float4*)&tmps[wave][c][0])[0];  // broadcast
      const float4 t1 = ((const float4*)&tmps[wave][c][0])[1];
      a[0] = fmaf(t0.x, w1r[c], a[0]);
      a[1] = fmaf(t0.y, w1r[c], a[1]);
      a[2] = fmaf(t0.z, w1r[c], a[2]);
      a[3] = fmaf(t0.w, w1r[c], a[3]);
      a[4] = fmaf(t1.x, w1r[c], a[4]);
      a[5] = fmaf(t1.y, w1r[c], a[5]);
      a[6] = fmaf(t1.z, w1r[c], a[6]);
      a[7] = fmaf(t1.w, w1r[c], a[7]);
    }
    {
      float4 h0, h1;
      h0.x = fmaxf(a[0], 0.f); h0.y = fmaxf(a[1], 0.f);
      h0.z = fmaxf(a[2], 0.f); h0.w = fmaxf(a[3], 0.f);
      h1.x = fmaxf(a[4], 0.f); h1.y = fmaxf(a[5], 0.f);
      h1.z = fmaxf(a[6], 0.f); h1.w = fmaxf(a[7], 0.f);
      __builtin_amdgcn_wave_barrier();
      ((float4*)&hs[wave][lane][0])[0] = h0;
      ((float4*)&hs[wave][lane][0])[1] = h1;
    }
    __builtin_amdgcn_wave_barrier();

    // ---- layer 2: msg = h @ W2 + b2 ----
    float m[EPW];
#pragma unroll
    for (int i = 0; i < EPW; ++i) m[i] = b2v;
#pragma unroll
    for (int j = 0; j < HID; ++j) {
      const float4 h0 = ((const float4*)&hs[wave][j][0])[0];  // broadcast
      const float4 h1 = ((const float4*)&hs[wave][j][0])[1];
      m[0] = fmaf(h0.x, w2r[j], m[0]);
      m[1] = fmaf(h0.y, w2r[j], m[1]);
      m[2] = fmaf(h0.z, w2r[j], m[2]);
      m[3] = fmaf(h0.w, w2r[j], m[3]);
      m[4] = fmaf(h1.x, w2r[j], m[4]);
      m[5] = fmaf(h1.y, w2r[j], m[5]);
      m[6] = fmaf(h1.z, w2r[j], m[6]);
      m[7] = fmaf(h1.w, w2r[j], m[7]);
    }

    // ---- max-scatter: fire-and-forget coalesced atomics ----
#pragma unroll
    for (int i = 0; i < EPW; ++i)
      if (dv[i] >= 0) atomicMax(&agg[dv[i] * HID + lane], ordenc(m[i]));
    __builtin_amdgcn_wave_barrier();
  }
}

// 16 nodes per block: decode agg (empty -> 0), out = sigmoid(agg @ Wo + bo)
__global__ __launch_bounds__(256) void out_kernel(
    const unsigned* __restrict__ agg,
    const float* __restrict__ Wo,  // [64, 16]
    const float* __restrict__ bo,  // [16]
    float* __restrict__ out,       // [N, 16]
    int N)
{
  __shared__ float Wos[HID * OUTF];
  __shared__ float bos[OUTF];
  __shared__ float aggs[16][HID + 1];

  for (int i = threadIdx.x; i < HID * OUTF; i += 256) Wos[i] = Wo[i];
  if (threadIdx.x < OUTF) bos[threadIdx.x] = bo[threadIdx.x];
  __syncthreads();

  const int nodeBase = blockIdx.x * 16;
  {
    int ln = threadIdx.x >> 4;
    int k0 = (threadIdx.x & 15) * 4;
    int n = nodeBase + ln;
    if (n < N) {
      const uint4 u = *(const uint4*)&agg[n * HID + k0];
      aggs[ln][k0 + 0] = (u.x == ORD_NEG_INF) ? 0.f : orddec(u.x);
      aggs[ln][k0 + 1] = (u.y == ORD_NEG_INF) ? 0.f : orddec(u.y);
      aggs[ln][k0 + 2] = (u.z == ORD_NEG_INF) ? 0.f : orddec(u.z);
      aggs[ln][k0 + 3] = (u.w == ORD_NEG_INF) ? 0.f : orddec(u.w);
    }
  }
  __syncthreads();
  {
    int ln = threadIdx.x >> 4;
    int o = threadIdx.x & 15;
    int n = nodeBase + ln;
    if (n < N) {
      float acc = bos[o];
#pragma unroll
      for (int k = 0; k < HID; ++k) acc = fmaf(aggs[ln][k], Wos[k * OUTF + o], acc);
      out[n * OUTF + o] = 1.f / (1.f + __expf(-acc));
    }
  }
}

extern "C" void kernel_launch(void* const* d_in, const int* in_sizes, int n_in,
                              void* d_out, int out_size, void* d_ws, size_t ws_size,
                              hipStream_t stream) {
  const float* x  = (const float*)d_in[0];
  const int*   ei = (const int*)d_in[1];
  const float* ea = (const float*)d_in[2];
  const float* W1 = (const float*)d_in[3];
  const float* b1 = (const float*)d_in[4];
  const float* W2 = (const float*)d_in[5];
  const float* b2 = (const float*)d_in[6];
  const float* Wo = (const float*)d_in[7];
  const float* bo = (const float*)d_in[8];
  float* out = (float*)d_out;

  const int N = in_sizes[0] / IN_F;   // 50000
  const int E = in_sizes[1] / 2;      // 1600000
  unsigned* agg = (unsigned*)d_ws;    // N*64*4 = 12.8 MB

  const int ntot = N * HID;
  init_agg_kernel<<<(ntot + 255) / 256, 256, 0, stream>>>(agg, ntot);
  edge_kernel<<<2048, 256, 0, stream>>>(x, ei, ea, W1, b1, W2, b2, agg, E);
  out_kernel<<<(N + 15) / 16, 256, 0, stream>>>(agg, Wo, bo, out, N);
}

// Round 4
// 1294.537 us; speedup vs baseline: 9.9507x; 9.9507x over previous
//
#include <hip/hip_runtime.h>

#define IN_F 32
#define HID 64
#define OUTF 16
#define EPW 4
#define ORD_NEG_INF 0x007FFFFFu    // ordenc(-inf)

// monotone float -> uint map so unsigned max == float max
__device__ __forceinline__ unsigned ordenc(float v) {
  unsigned b = __float_as_uint(v);
  return (b & 0x80000000u) ? ~b : (b | 0x80000000u);
}
__device__ __forceinline__ float orddec(unsigned u) {
  unsigned b = (u & 0x80000000u) ? (u & 0x7FFFFFFFu) : ~u;
  return __uint_as_float(b);
}

__global__ __launch_bounds__(256) void init_agg_kernel(unsigned* __restrict__ agg, int n) {
  int i = blockIdx.x * blockDim.x + threadIdx.x;
  if (i < n) agg[i] = ORD_NEG_INF;
}

// Per-node precompute: P[n] = x[n] @ (W1A - W1B) + b1,  Q[n] = x[n] @ W1B
// (layer1 preact for edge (s,d) is then P[d] + Q[s] + ea @ W1C)
__global__ __launch_bounds__(256) void node_pre_kernel(
    const float* __restrict__ x,   // [N, 32]
    const float* __restrict__ W1,  // [67, 64]
    const float* __restrict__ b1,  // [64]
    float* __restrict__ P,         // [N, 64]
    float* __restrict__ Q,         // [N, 64]
    int N)
{
  const int lane = threadIdx.x & 63;
  float w1d[IN_F], w1b[IN_F];
#pragma unroll
  for (int c = 0; c < IN_F; ++c) {
    w1b[c] = W1[(IN_F + c) * HID + lane];
    w1d[c] = W1[c * HID + lane] - w1b[c];
  }
  const float b1v = b1[lane];

  int gw = __builtin_amdgcn_readfirstlane((blockIdx.x << 2) | (threadIdx.x >> 6));
  const int nwaves = gridDim.x << 2;
  for (int n = gw; n < N; n += nwaves) {
    float p = b1v, q = 0.f;
#pragma unroll
    for (int c = 0; c < IN_F; ++c) {
      float xv = x[n * IN_F + c];   // wave-uniform -> scalar load
      p = fmaf(xv, w1d[c], p);
      q = fmaf(xv, w1b[c], q);
    }
    P[n * HID + lane] = p;
    Q[n * HID + lane] = q;
  }
}

// Edge kernel: lane owns channel. No W1 in registers; layer1 = P[dst]+Q[src]+ea@W1C.
// 3-deep pipeline: indices 2 iters ahead (scalar loads), P/Q/ea values 1 iter ahead.
// No block barriers — all LDS traffic is per-wave.
__global__ __launch_bounds__(256) void edge_kernel(
    const int* __restrict__ ei,            // [2, E]
    const float* __restrict__ ea,          // [E, 3]
    const float* __restrict__ W1,          // [67, 64] (only rows 64..66 used)
    const float* __restrict__ W2,          // [64, 64]
    const float* __restrict__ b2,          // [64]
    const float* __restrict__ P,           // [N, 64]
    const float* __restrict__ Q,           // [N, 64]
    unsigned* __restrict__ agg,            // [N, 64] ord-encoded
    int E)
{
  __shared__ float hs[4][HID][EPW];   // [wave][j][edge] 4 KB

  const int wave = threadIdx.x >> 6;
  const int lane = threadIdx.x & 63;

  float w2r[HID];
#pragma unroll
  for (int j = 0; j < HID; ++j) w2r[j] = W2[j * HID + lane];
  const float b2v  = b2[lane];
  const float w1c0 = W1[(2 * IN_F + 0) * HID + lane];
  const float w1c1 = W1[(2 * IN_F + 1) * HID + lane];
  const float w1c2 = W1[(2 * IN_F + 2) * HID + lane];

  const int gwave = __builtin_amdgcn_readfirstlane((blockIdx.x << 2) | wave);
  const int stride = gridDim.x * 4 * EPW;

  int s1[EPW], d1[EPW];                 // indices for current iter
  int s2[EPW], d2[EPW];                 // indices for next iter
  float p1[EPW], q1[EPW], ea1[EPW][3];  // values for current iter

  int e0 = gwave * EPW;
  // ---- preamble ----
#pragma unroll
  for (int i = 0; i < EPW; ++i) {
    int e = e0 + i;
    if (e < E) { s1[i] = ei[e]; d1[i] = ei[E + e]; } else { s1[i] = 0; d1[i] = -1; }
  }
#pragma unroll
  for (int i = 0; i < EPW; ++i) {
    if (d1[i] >= 0) {
      int e = e0 + i;
      p1[i] = P[d1[i] * HID + lane];
      q1[i] = Q[s1[i] * HID + lane];
      ea1[i][0] = ea[e * 3 + 0]; ea1[i][1] = ea[e * 3 + 1]; ea1[i][2] = ea[e * 3 + 2];
    } else { p1[i] = 0.f; q1[i] = 0.f; ea1[i][0] = ea1[i][1] = ea1[i][2] = 0.f; }
  }
#pragma unroll
  for (int i = 0; i < EPW; ++i) {
    int e = e0 + stride + i;
    if (e < E) { s2[i] = ei[e]; d2[i] = ei[E + e]; } else { s2[i] = 0; d2[i] = -1; }
  }

  for (; e0 < E; e0 += stride) {
    // ---- layer 1 for current iter (all in registers) + stage h to LDS ----
    float hv[EPW];
#pragma unroll
    for (int i = 0; i < EPW; ++i) {
      float pre = p1[i] + q1[i];
      pre = fmaf(ea1[i][0], w1c0, pre);
      pre = fmaf(ea1[i][1], w1c1, pre);
      pre = fmaf(ea1[i][2], w1c2, pre);
      hv[i] = fmaxf(pre, 0.f);
    }
    float4 hq; hq.x = hv[0]; hq.y = hv[1]; hq.z = hv[2]; hq.w = hv[3];
    *(float4*)&hs[wave][lane][0] = hq;

    int dcur[EPW];
#pragma unroll
    for (int i = 0; i < EPW; ++i) dcur[i] = d1[i];

    // ---- prefetch: values for next iter (idx already resident), idx 2 ahead ----
#pragma unroll
    for (int i = 0; i < EPW; ++i) { s1[i] = s2[i]; d1[i] = d2[i]; }
#pragma unroll
    for (int i = 0; i < EPW; ++i) {
      if (d1[i] >= 0) {
        int e = e0 + stride + i;
        p1[i] = P[d1[i] * HID + lane];
        q1[i] = Q[s1[i] * HID + lane];
        ea1[i][0] = ea[e * 3 + 0]; ea1[i][1] = ea[e * 3 + 1]; ea1[i][2] = ea[e * 3 + 2];
      }
    }
#pragma unroll
    for (int i = 0; i < EPW; ++i) {
      int e = e0 + 2 * stride + i;
      if (e < E) { s2[i] = ei[e]; d2[i] = ei[E + e]; } else { s2[i] = 0; d2[i] = -1; }
    }

    // ---- layer 2: msg = h @ W2 + b2 (broadcast LDS reads, conflict-free) ----
    float m[EPW];
#pragma unroll
    for (int i = 0; i < EPW; ++i) m[i] = b2v;
#pragma unroll
    for (int j = 0; j < HID; ++j) {
      const float4 hh = *(const float4*)&hs[wave][j][0];
      m[0] = fmaf(hh.x, w2r[j], m[0]);
      m[1] = fmaf(hh.y, w2r[j], m[1]);
      m[2] = fmaf(hh.z, w2r[j], m[2]);
      m[3] = fmaf(hh.w, w2r[j], m[3]);
    }

    // ---- max-scatter: fire-and-forget coalesced atomics ----
#pragma unroll
    for (int i = 0; i < EPW; ++i)
      if (dcur[i] >= 0) atomicMax(&agg[dcur[i] * HID + lane], ordenc(m[i]));
  }
}

// 16 nodes per block: decode agg (empty -> 0), out = sigmoid(agg @ Wo + bo)
__global__ __launch_bounds__(256) void out_kernel(
    const unsigned* __restrict__ agg,
    const float* __restrict__ Wo,  // [64, 16]
    const float* __restrict__ bo,  // [16]
    float* __restrict__ out,       // [N, 16]
    int N)
{
  __shared__ float Wos[HID * OUTF];
  __shared__ float bos[OUTF];
  __shared__ float aggs[16][HID + 1];

  for (int i = threadIdx.x; i < HID * OUTF; i += 256) Wos[i] = Wo[i];
  if (threadIdx.x < OUTF) bos[threadIdx.x] = bo[threadIdx.x];
  __syncthreads();

  const int nodeBase = blockIdx.x * 16;
  {
    int ln = threadIdx.x >> 4;
    int k0 = (threadIdx.x & 15) * 4;
    int n = nodeBase + ln;
    if (n < N) {
      const uint4 u = *(const uint4*)&agg[n * HID + k0];
      aggs[ln][k0 + 0] = (u.x == ORD_NEG_INF) ? 0.f : orddec(u.x);
      aggs[ln][k0 + 1] = (u.y == ORD_NEG_INF) ? 0.f : orddec(u.y);
      aggs[ln][k0 + 2] = (u.z == ORD_NEG_INF) ? 0.f : orddec(u.z);
      aggs[ln][k0 + 3] = (u.w == ORD_NEG_INF) ? 0.f : orddec(u.w);
    }
  }
  __syncthreads();
  {
    int ln = threadIdx.x >> 4;
    int o = threadIdx.x & 15;
    int n = nodeBase + ln;
    if (n < N) {
      float acc = bos[o];
#pragma unroll
      for (int k = 0; k < HID; ++k) acc = fmaf(aggs[ln][k], Wos[k * OUTF + o], acc);
      out[n * OUTF + o] = 1.f / (1.f + __expf(-acc));
    }
  }
}

extern "C" void kernel_launch(void* const* d_in, const int* in_sizes, int n_in,
                              void* d_out, int out_size, void* d_ws, size_t ws_size,
                              hipStream_t stream) {
  const float* x  = (const float*)d_in[0];
  const int*   ei = (const int*)d_in[1];
  const float* ea = (const float*)d_in[2];
  const float* W1 = (const float*)d_in[3];
  const float* b1 = (const float*)d_in[4];
  const float* W2 = (const float*)d_in[5];
  const float* b2 = (const float*)d_in[6];
  const float* Wo = (const float*)d_in[7];
  const float* bo = (const float*)d_in[8];
  float* out = (float*)d_out;

  const int N = in_sizes[0] / IN_F;   // 50000
  const int E = in_sizes[1] / 2;      // 1600000

  float*    Pp  = (float*)d_ws;                // N*64*4 = 12.8 MB
  float*    Qp  = Pp + (size_t)N * HID;        // 12.8 MB
  unsigned* agg = (unsigned*)(Qp + (size_t)N * HID);  // 12.8 MB

  const int ntot = N * HID;
  init_agg_kernel<<<(ntot + 255) / 256, 256, 0, stream>>>(agg, ntot);
  node_pre_kernel<<<512, 256, 0, stream>>>(x, W1, b1, Pp, Qp, N);
  edge_kernel<<<2048, 256, 0, stream>>>(ei, ea, W1, W2, b2, Pp, Qp, agg, E);
  out_kernel<<<(N + 15) / 16, 256, 0, stream>>>(agg, Wo, bo, out, N);
}

// Round 5
// 391.735 us; speedup vs baseline: 32.8833x; 3.3046x over previous
//
#include <hip/hip_runtime.h>

#define IN_F 32
#define HID 64
#define OUTF 16
#define EPW 16                     // edges per wave per iteration (one MFMA M-tile)
#define ORD_NEG_INF 0x007FFFFFu    // ordenc(-inf)

typedef _Float16 v8h __attribute__((ext_vector_type(8)));
typedef float v4f __attribute__((ext_vector_type(4)));

// monotone float -> uint map so unsigned max == float max
__device__ __forceinline__ unsigned ordenc(float v) {
  unsigned b = __float_as_uint(v);
  return (b & 0x80000000u) ? ~b : (b | 0x80000000u);
}
__device__ __forceinline__ float orddec(unsigned u) {
  unsigned b = (u & 0x80000000u) ? (u & 0x7FFFFFFFu) : ~u;
  return __uint_as_float(b);
}

__global__ __launch_bounds__(256) void init_agg_kernel(unsigned* __restrict__ agg, int n) {
  int i = blockIdx.x * blockDim.x + threadIdx.x;
  if (i < n) agg[i] = ORD_NEG_INF;
}

// Per-node precompute: P[n] = x[n] @ (W1A - W1B) + b1,  Q[n] = x[n] @ W1B
__global__ __launch_bounds__(256) void node_pre_kernel(
    const float* __restrict__ x, const float* __restrict__ W1,
    const float* __restrict__ b1, float* __restrict__ P, float* __restrict__ Q, int N)
{
  const int lane = threadIdx.x & 63;
  float w1d[IN_F], w1b[IN_F];
#pragma unroll
  for (int c = 0; c < IN_F; ++c) {
    w1b[c] = W1[(IN_F + c) * HID + lane];
    w1d[c] = W1[c * HID + lane] - w1b[c];
  }
  const float b1v = b1[lane];
  int gw = __builtin_amdgcn_readfirstlane((blockIdx.x << 2) | (threadIdx.x >> 6));
  const int nwaves = gridDim.x << 2;
  for (int n = gw; n < N; n += nwaves) {
    float p = b1v, q = 0.f;
#pragma unroll
    for (int c = 0; c < IN_F; ++c) {
      float xv = x[n * IN_F + c];
      p = fmaf(xv, w1d[c], p);
      q = fmaf(xv, w1b[c], q);
    }
    P[n * HID + lane] = p;
    Q[n * HID + lane] = q;
  }
}

// Edge kernel, MFMA layer2.
// Per iteration a wave does 16 edges:
//   layer1 (lane=channel): pre = P[d]+Q[s]+ea@W1C, h=relu -> fp16 -> hB[edge][ch] LDS
//   layer2: D[out][edge] = W2^T (A, regs) x hB (B, LDS) via 8x mfma_f32_16x16x32_f16
//   D -> msg LDS (scatter) -> coalesced per-edge rows -> +b2 -> ordenc -> atomicMax
__global__ __launch_bounds__(256) void edge_kernel(
    const int* __restrict__ ei,            // [2, E]
    const float* __restrict__ ea,          // [E, 3]
    const float* __restrict__ W1,          // [67, 64] (rows 64..66 used)
    const float* __restrict__ W2,          // [64, 64]
    const float* __restrict__ b2,          // [64]
    const float* __restrict__ P,           // [N, 64]
    const float* __restrict__ Q,           // [N, 64]
    unsigned* __restrict__ agg,            // [N, 64] ord-encoded
    int E)
{
  __shared__ __align__(16) _Float16 hB[4][EPW][72];  // [wave][edge][ch], stride 72 (16B-aligned rows)
  __shared__ __align__(16) float msgS[4][EPW][65];   // [wave][edge][ch], stride 65 (conflict break)

  const int wave = threadIdx.x >> 6;
  const int lane = threadIdx.x & 63;
  const int quad = lane >> 4;
  const int eidx = lane & 15;

  // A-operand: W2^T fragments, fp16, loop-invariant.
  // a_frag[t][ks][j] = W2T[m=t*16+eidx][k=ks*32+quad*8+j] = W2[(ks*32+quad*8+j)*64 + t*16+eidx]
  v8h a_frag[4][2];
#pragma unroll
  for (int t = 0; t < 4; ++t)
#pragma unroll
    for (int ks = 0; ks < 2; ++ks)
#pragma unroll
      for (int j = 0; j < 8; ++j)
        a_frag[t][ks][j] = (_Float16)W2[(ks * 32 + quad * 8 + j) * HID + t * 16 + eidx];

  const float w1c0 = W1[(2 * IN_F + 0) * HID + lane];
  const float w1c1 = W1[(2 * IN_F + 1) * HID + lane];
  const float w1c2 = W1[(2 * IN_F + 2) * HID + lane];
  const float b2v  = b2[lane];

  const int gwave = __builtin_amdgcn_readfirstlane((blockIdx.x << 2) | wave);
  const int stride = gridDim.x * 4 * EPW;

  int scur[EPW], dcur[EPW];
  float pv[EPW], qv[EPW];
  float ea0[EPW], ea1[EPW], ea2[EPW];

  int e0 = gwave * EPW;
  // ---- preamble: indices, gathers, ea for iteration 0 ----
#pragma unroll
  for (int i = 0; i < EPW; ++i) {
    int e = e0 + i;
    bool v = e < E;
    int ec = v ? e : 0;
    scur[i] = ei[ec];
    dcur[i] = v ? ei[(size_t)E + ec] : -1;
  }
#pragma unroll
  for (int i = 0; i < EPW; ++i) {
    int d = dcur[i] < 0 ? 0 : dcur[i];
    pv[i] = P[d * HID + lane];
    qv[i] = Q[scur[i] * HID + lane];
  }
#pragma unroll
  for (int i = 0; i < EPW; ++i) {
    int e = min(e0 + i, E - 1);
    ea0[i] = ea[e * 3 + 0]; ea1[i] = ea[e * 3 + 1]; ea2[i] = ea[e * 3 + 2];
  }

  while (e0 < E) {
    const int e1 = e0 + stride;

    // ---- layer 1 (lane = channel) -> fp16 -> hB[edge][ch] ----
    int datm[EPW];
#pragma unroll
    for (int i = 0; i < EPW; ++i) {
      datm[i] = dcur[i];
      float pre = pv[i] + qv[i];
      pre = fmaf(ea0[i], w1c0, pre);
      pre = fmaf(ea1[i], w1c1, pre);
      pre = fmaf(ea2[i], w1c2, pre);
      hB[wave][i][lane] = (_Float16)fmaxf(pre, 0.f);   // ds_write_b16, 2-way max
    }

    // ---- prefetch next iteration (indices scalar; gathers land during mfma) ----
#pragma unroll
    for (int i = 0; i < EPW; ++i) {
      int e = e1 + i;
      bool v = e < E;
      int ec = v ? e : 0;
      scur[i] = ei[ec];
      dcur[i] = v ? ei[(size_t)E + ec] : -1;
    }
#pragma unroll
    for (int i = 0; i < EPW; ++i) {
      int d = dcur[i] < 0 ? 0 : dcur[i];
      pv[i] = P[d * HID + lane];
      qv[i] = Q[scur[i] * HID + lane];
    }
#pragma unroll
    for (int i = 0; i < EPW; ++i) {
      int e = min(e1 + i, E - 1);
      ea0[i] = ea[e * 3 + 0]; ea1[i] = ea[e * 3 + 1]; ea2[i] = ea[e * 3 + 2];
    }

    __builtin_amdgcn_wave_barrier();

    // ---- layer 2: 8x mfma. B-frag: hB[edge=eidx][k=ks*32+quad*8 ..+7] ----
    const v8h bf0 = *(const v8h*)&hB[wave][eidx][quad * 8];
    const v8h bf1 = *(const v8h*)&hB[wave][eidx][32 + quad * 8];
    v4f acc[4];
#pragma unroll
    for (int t = 0; t < 4; ++t) {
      acc[t] = (v4f){0.f, 0.f, 0.f, 0.f};
      acc[t] = __builtin_amdgcn_mfma_f32_16x16x32_f16(a_frag[t][0], bf0, acc[t], 0, 0, 0);
      acc[t] = __builtin_amdgcn_mfma_f32_16x16x32_f16(a_frag[t][1], bf1, acc[t], 0, 0, 0);
    }

    // ---- D-frags -> msgS: D[m=out][n=edge]: col=eidx(edge), row=quad*4+r (out-ch in tile) ----
#pragma unroll
    for (int t = 0; t < 4; ++t)
#pragma unroll
      for (int r = 0; r < 4; ++r)
        msgS[wave][eidx][t * 16 + quad * 4 + r] = acc[t][r];

    __builtin_amdgcn_wave_barrier();

    // ---- coalesced readback + bias + ordenc + 64-lane atomic per edge ----
#pragma unroll
    for (int i = 0; i < EPW; ++i) {
      if (datm[i] >= 0) {
        float mv = msgS[wave][i][lane] + b2v;
        atomicMax(&agg[datm[i] * HID + lane], ordenc(mv));
      }
    }
    e0 = e1;
  }
}

// 16 nodes per block: decode agg (empty -> 0), out = sigmoid(agg @ Wo + bo)
__global__ __launch_bounds__(256) void out_kernel(
    const unsigned* __restrict__ agg,
    const float* __restrict__ Wo, const float* __restrict__ bo,
    float* __restrict__ out, int N)
{
  __shared__ float Wos[HID * OUTF];
  __shared__ float bos[OUTF];
  __shared__ float aggs[16][HID + 1];

  for (int i = threadIdx.x; i < HID * OUTF; i += 256) Wos[i] = Wo[i];
  if (threadIdx.x < OUTF) bos[threadIdx.x] = bo[threadIdx.x];
  __syncthreads();

  const int nodeBase = blockIdx.x * 16;
  {
    int ln = threadIdx.x >> 4;
    int k0 = (threadIdx.x & 15) * 4;
    int n = nodeBase + ln;
    if (n < N) {
      const uint4 u = *(const uint4*)&agg[n * HID + k0];
      aggs[ln][k0 + 0] = (u.x == ORD_NEG_INF) ? 0.f : orddec(u.x);
      aggs[ln][k0 + 1] = (u.y == ORD_NEG_INF) ? 0.f : orddec(u.y);
      aggs[ln][k0 + 2] = (u.z == ORD_NEG_INF) ? 0.f : orddec(u.z);
      aggs[ln][k0 + 3] = (u.w == ORD_NEG_INF) ? 0.f : orddec(u.w);
    }
  }
  __syncthreads();
  {
    int ln = threadIdx.x >> 4;
    int o = threadIdx.x & 15;
    int n = nodeBase + ln;
    if (n < N) {
      float acc = bos[o];
#pragma unroll
      for (int k = 0; k < HID; ++k) acc = fmaf(aggs[ln][k], Wos[k * OUTF + o], acc);
      out[n * OUTF + o] = 1.f / (1.f + __expf(-acc));
    }
  }
}

extern "C" void kernel_launch(void* const* d_in, const int* in_sizes, int n_in,
                              void* d_out, int out_size, void* d_ws, size_t ws_size,
                              hipStream_t stream) {
  const float* x  = (const float*)d_in[0];
  const int*   ei = (const int*)d_in[1];
  const float* ea = (const float*)d_in[2];
  const float* W1 = (const float*)d_in[3];
  const float* b1 = (const float*)d_in[4];
  const float* W2 = (const float*)d_in[5];
  const float* b2 = (const float*)d_in[6];
  const float* Wo = (const float*)d_in[7];
  const float* bo = (const float*)d_in[8];
  float* out = (float*)d_out;

  const int N = in_sizes[0] / IN_F;   // 50000
  const int E = in_sizes[1] / 2;      // 1600000

  float*    Pp  = (float*)d_ws;
  float*    Qp  = Pp + (size_t)N * HID;
  unsigned* agg = (unsigned*)(Qp + (size_t)N * HID);

  const int ntot = N * HID;
  init_agg_kernel<<<(ntot + 255) / 256, 256, 0, stream>>>(agg, ntot);
  node_pre_kernel<<<512, 256, 0, stream>>>(x, W1, b1, Pp, Qp, N);
  edge_kernel<<<2048, 256, 0, stream>>>(ei, ea, W1, W2, b2, Pp, Qp, agg, E);
  out_kernel<<<(N + 15) / 16, 256, 0, stream>>>(agg, Wo, bo, out, N);
}